// Round 10
// baseline (38.525 us; speedup 1.0000x reference)
//
#include <hip/hip_runtime.h>

// Problem constants (match reference: B=8192, S=7, C=30)
// DIAGNOSTIC ROUND: identical structure to R8 (best, 25.27us) but the tile
// walk runs TWICE (second pass mostly L3-resident) so the main kernel exceeds
// the harness's 39us fill dispatches and surfaces in the rocprof top-5.
// Output = (2x sum)/2 -> numerically equivalent.
#define YB      8192
#define YS      7
#define YC      30
#define NCELLS  (YB * YS * YS)        // 401408
#define TCELLS  32                    // cells per wave-tile
#define TBYTES  (TCELLS * YC * 4)     // 3840 B per array per tile
#define TFLOATS (TCELLS * YC)         // 960 floats
#define NTILES  (NCELLS / TCELLS)     // 12544, divides exactly
#define BLOCK   256
#define GRID    512                   // 2 blocks/CU exactly
#define NWAVES  (GRID * 4)            // 2048 waves

__device__ __forceinline__ float iou_quirk(float cx1, float cy1, float w1, float h1,
                                           float cx2, float cy2, float w2, float h2) {
    float area1 = w1 * h1;
    float area2 = w2 * h2;
    float max_left   = fmaxf(cx1 - w1 * 0.5f, cx2 - w2 * 0.5f);
    float min_right  = fminf(cx1 + w1 * 0.5f, cx2 + w2 * 0.5f);
    float max_top    = fmaxf(cy1 - h1 * 0.5f, cy2 - h2 * 0.5f);
    float min_bottom = fminf(cy1 + h1 * 0.5f, cy2 + h2 * 0.5f);
    float inter = (min_right - max_left) * (min_bottom - max_top);
    bool overlap = (max_left < min_right) && (max_top < min_bottom);
    return overlap ? (inter / area1 + area2 - inter) : 0.0f;
}

__device__ __forceinline__ float cell_loss(const float* __restrict__ sp,
                                           const float* __restrict__ sl, int lane) {
    if (lane >= TCELLS) return 0.0f;
    const float2* p2 = (const float2*)(sp + lane * YC);
    const float2* l2 = (const float2*)(sl + lane * YC);

    float pv[10], lv[10];
    #pragma unroll
    for (int i = 0; i < 5; ++i) {
        float2 a = p2[i]; pv[2 * i] = a.x; pv[2 * i + 1] = a.y;
        float2 b = l2[i]; lv[2 * i] = b.x; lv[2 * i + 1] = b.y;
    }
    float loss_cls = 0.0f;
    #pragma unroll
    for (int i = 5; i < 15; ++i) {
        float2 a = p2[i], b = l2[i];
        float dx = a.x - b.x, dy = a.y - b.y;
        loss_cls += dx * dx + dy * dy;
    }

    float iou1 = iou_quirk(pv[0], pv[1], pv[2], pv[3], lv[0], lv[1], lv[2], lv[3]);
    float iou2 = iou_quirk(pv[5], pv[6], pv[7], pv[8], lv[5], lv[6], lv[7], lv[8]);
    bool resp1 = iou1 > iou2;

    float dx1 = pv[0] - lv[0], dy1 = pv[1] - lv[1];
    float xy1 = dx1 * dx1 + dy1 * dy1;
    float dx2 = pv[5] - lv[5], dy2 = pv[6] - lv[6];
    float xy2 = dx2 * dx2 + dy2 * dy2;

    float sw1 = sqrtf(pv[2]) - sqrtf(lv[2]), sh1 = sqrtf(pv[3]) - sqrtf(lv[3]);
    float wh1 = sw1 * sw1 + sh1 * sh1;
    float sw2 = sqrtf(pv[7]) - sqrtf(lv[7]), sh2 = sqrtf(pv[8]) - sqrtf(lv[8]);
    float wh2 = sw2 * sw2 + sh2 * sh2;

    float d1 = pv[4] - iou1, d2 = pv[9] - iou2;
    float e1 = d1 * d1, e2 = d2 * d2;

    float obj_cell = 5.0f * (resp1 ? xy1 : xy2)
                   + (resp1 ? wh1 : wh2)
                   + (resp1 ? e1 : e2)
                   + 0.5f * (resp1 ? e2 : e1)
                   + loss_cls;
    float noobj_cell = 0.5f * (pv[4] * pv[4] + pv[9] * pv[9]);

    return (lv[4] == 1.0f) ? obj_cell : noobj_cell;
}

__global__ __launch_bounds__(BLOCK) void yolo_partial_kernel(const float* __restrict__ preds,
                                                             const float* __restrict__ labels,
                                                             float* __restrict__ partial) {
    // Per-wave private double-buffered tiles, counted-vmcnt pipeline (R8).
    __shared__ float lds[4][2][2][TFLOATS];   // 61440 B -> 2 blocks/CU

    const int tid  = threadIdx.x;
    const int lane = tid & 63;
    const int w    = tid >> 6;
    const int wave_id = blockIdx.x * 4 + w;

    float acc = 0.0f;

#if defined(__has_builtin) && __has_builtin(__builtin_amdgcn_global_load_lds)
    typedef const __attribute__((address_space(1))) char* g_t;
    typedef __attribute__((address_space(3))) char* s_t;

    #define STAGE_ARR(gbase, sbase)                                                        \
        do {                                                                               \
            __builtin_amdgcn_global_load_lds((g_t)((gbase) + lane * 16),                   \
                                             (s_t)((sbase) + lane * 16), 16, 0, 0);        \
            __builtin_amdgcn_global_load_lds((g_t)((gbase) + 1024 + lane * 16),            \
                                             (s_t)((sbase) + 1024 + lane * 16), 16, 0, 0); \
            __builtin_amdgcn_global_load_lds((g_t)((gbase) + 2048 + lane * 16),            \
                                             (s_t)((sbase) + 2048 + lane * 16), 16, 0, 0); \
            __builtin_amdgcn_global_load_lds((g_t)((gbase) + 3072 + lane * 4),             \
                                             (s_t)((sbase) + 3072 + lane * 4), 4, 0, 0);   \
            __builtin_amdgcn_global_load_lds((g_t)((gbase) + 3328 + lane * 4),             \
                                             (s_t)((sbase) + 3328 + lane * 4), 4, 0, 0);   \
            __builtin_amdgcn_global_load_lds((g_t)((gbase) + 3584 + lane * 4),             \
                                             (s_t)((sbase) + 3584 + lane * 4), 4, 0, 0);   \
        } while (0)

    #define STAGE_TILE(tile, b)                                                            \
        do {                                                                               \
            const char* gp_ = (const char*)preds  + (size_t)(tile) * TBYTES;               \
            const char* gl_ = (const char*)labels + (size_t)(tile) * TBYTES;               \
            STAGE_ARR(gp_, (char*)&lds[w][(b)][0][0]);                                     \
            STAGE_ARR(gl_, (char*)&lds[w][(b)][1][0]);                                     \
        } while (0)

    int buf = 0;
    #pragma unroll 1
    for (int pass = 0; pass < 2; ++pass) {
        int t = wave_id;
        STAGE_TILE(t, buf);
        for (;;) {
            const int tn = t + NWAVES;
            if (tn >= NTILES) break;
            STAGE_TILE(tn, buf ^ 1);
            asm volatile("s_waitcnt vmcnt(12)" ::: "memory");
            __builtin_amdgcn_sched_barrier(0);
            acc += cell_loss(&lds[w][buf][0][0], &lds[w][buf][1][0], lane);
            buf ^= 1;
            t = tn;
        }
        asm volatile("s_waitcnt vmcnt(0)" ::: "memory");
        __builtin_amdgcn_sched_barrier(0);
        acc += cell_loss(&lds[w][buf][0][0], &lds[w][buf][1][0], lane);
        buf ^= 1;
    }

    #undef STAGE_TILE
    #undef STAGE_ARR
#else
    for (int pass = 0; pass < 2; ++pass) {
        for (int t = wave_id, buf = 0; t < NTILES; t += NWAVES, buf ^= 1) {
            const float4* gp = (const float4*)((const char*)preds  + (size_t)t * TBYTES);
            const float4* gl = (const float4*)((const char*)labels + (size_t)t * TBYTES);
            float4* sp4 = (float4*)&lds[w][buf][0][0];
            float4* sl4 = (float4*)&lds[w][buf][1][0];
            for (int i = lane; i < TFLOATS / 4; i += 64) { sp4[i] = gp[i]; sl4[i] = gl[i]; }
            asm volatile("s_waitcnt vmcnt(0) lgkmcnt(0)" ::: "memory");
            __builtin_amdgcn_sched_barrier(0);
            acc += cell_loss(&lds[w][buf][0][0], &lds[w][buf][1][0], lane);
        }
    }
#endif

    // Deterministic wave64 shuffle-tree reduction; one partial per wave.
    for (int off = 32; off > 0; off >>= 1) acc += __shfl_down(acc, off);
    if (lane == 0) partial[wave_id] = acc;
}

__global__ __launch_bounds__(BLOCK) void yolo_final_kernel(const float* __restrict__ partial,
                                                           float* __restrict__ out) {
    __shared__ double w[BLOCK / 64];
    double s = 0.0;
    for (int i = threadIdx.x; i < NWAVES; i += BLOCK) s += (double)partial[i];
    for (int off = 32; off > 0; off >>= 1) s += __shfl_down(s, off);
    const int lane = threadIdx.x & 63, wid = threadIdx.x >> 6;
    if (lane == 0) w[wid] = s;
    __syncthreads();
    // Two passes accumulated -> divide by 2*YB.
    if (threadIdx.x == 0) out[0] = (float)((w[0] + w[1] + w[2] + w[3]) / (double)(2 * YB));
}

extern "C" void kernel_launch(void* const* d_in, const int* in_sizes, int n_in,
                              void* d_out, int out_size, void* d_ws, size_t ws_size,
                              hipStream_t stream) {
    const float* preds  = (const float*)d_in[0];
    const float* labels = (const float*)d_in[1];
    float* out = (float*)d_out;
    float* partial = (float*)d_ws;   // needs NWAVES*4 = 8192 bytes

    yolo_partial_kernel<<<GRID, BLOCK, 0, stream>>>(preds, labels, partial);
    yolo_final_kernel<<<1, BLOCK, 0, stream>>>(partial, out);
}